// Round 3
// baseline (492.044 us; speedup 1.0000x reference)
//
#include <hip/hip_runtime.h>
#include <hip/hip_bf16.h>
#include <stdint.h>

typedef _Float16 f16x8 __attribute__((ext_vector_type(8)));
typedef __fp16 fp16x2 __attribute__((ext_vector_type(2)));
typedef float f32x4 __attribute__((ext_vector_type(4)));

#define B_DIM 16
#define TD 1024
#define TE 1024
#define DD 1024

__device__ __forceinline__ uint32_t pk2(float a, float b) {
  fp16x2 h = __builtin_amdgcn_cvt_pkrtz(a, b);
  return __builtin_bit_cast(uint32_t, h);
}

// ---------------------------------------------------------------------------
// K1: S[t][e] = sum_d dec[b,t,d] * enc[b,e,d], single-pass fp16 MFMA.
// 128x128 C-tile, BK=32, 4 waves 2x2, each wave 4x4 of 16x16x32 MFMAs.
// LDS tiles pitch 40 halves (20 dw) for near-perfect bank spread.
// S written fp32 to out[b, t, 1024+e].
// ---------------------------------------------------------------------------
__global__ __launch_bounds__(256, 2)
void k1_scores(const float* __restrict__ dec, const float* __restrict__ enc,
               float* __restrict__ out) {
  __shared__ uint32_t AS[128 * 20], BS[128 * 20];
  const int tid = threadIdx.x, lane = tid & 63, wave = tid >> 6;
  const int wm = wave >> 1, wn = wave & 1;
  const int b = blockIdx.z;
  const int t0 = blockIdx.y * 128, e0 = blockIdx.x * 128;
  const float* A = dec + (size_t)b * TD * DD;
  const float* Bm = enc + (size_t)b * TE * DD;

  // staging: inst j covers chunk c = tid + 256*j; row r = c>>3 = r0+32j,
  // float4-col c4 = tid&7. Per-inst: 1KB contiguous global, spread LDS banks.
  const int r0 = tid >> 3, c4 = tid & 7;
  const float* aptr = A + (size_t)(t0 + r0) * DD + c4 * 4;
  const float* bptr = Bm + (size_t)(e0 + r0) * DD + c4 * 4;
  const int wls = r0 * 20 + c4 * 2;

  const int lr = lane & 15, q = lane >> 4;
  int aoff[4], boff[4];
#pragma unroll
  for (int i = 0; i < 4; ++i) {
    aoff[i] = (wm * 64 + i * 16 + lr) * 20 + q * 4;  // dword offsets
    boff[i] = (wn * 64 + i * 16 + lr) * 20 + q * 4;
  }

  f32x4 acc[4][4] = {};

  for (int k0 = 0; k0 < DD; k0 += 32) {
#pragma unroll
    for (int j = 0; j < 4; ++j) {
      const float4 va = *(const float4*)(aptr + (size_t)(32 * j) * DD);
      const float4 vb = *(const float4*)(bptr + (size_t)(32 * j) * DD);
      *(uint2*)&AS[wls + j * 640] = make_uint2(pk2(va.x, va.y), pk2(va.z, va.w));
      *(uint2*)&BS[wls + j * 640] = make_uint2(pk2(vb.x, vb.y), pk2(vb.z, vb.w));
    }
    __syncthreads();

    f16x8 af[4];
#pragma unroll
    for (int mi = 0; mi < 4; ++mi) af[mi] = *(const f16x8*)&AS[aoff[mi]];
#pragma unroll
    for (int ni = 0; ni < 4; ++ni) {
      f16x8 bf = *(const f16x8*)&BS[boff[ni]];
#pragma unroll
      for (int mi = 0; mi < 4; ++mi)
        acc[mi][ni] =
            __builtin_amdgcn_mfma_f32_16x16x32_f16(af[mi], bf, acc[mi][ni], 0, 0, 0);
    }
    __syncthreads();
    aptr += 32;
    bptr += 32;
  }

  // C/D layout: col(n=e) = lane&15, row(m=t) = (lane>>4)*4 + reg
  float* outb = out + (size_t)b * TD * 2048 + 1024;
  const int tb = t0 + wm * 64 + q * 4;
  const int eb = e0 + wn * 64 + lr;
#pragma unroll
  for (int mi = 0; mi < 4; ++mi)
#pragma unroll
    for (int ni = 0; ni < 4; ++ni)
#pragma unroll
      for (int i = 0; i < 4; ++i)
        outb[(size_t)(tb + mi * 16 + i) * 2048 + (eb + ni * 16)] = acc[mi][ni][i];
}

// ---------------------------------------------------------------------------
// K2: softmax over e for each (b,t) row. Reads fp32 S from out[row,1024:2048],
// writes fp16 P (1024 halves = 2KB) into the first quarter of the row.
// One wave per row, 4 rows per block.
// ---------------------------------------------------------------------------
__global__ __launch_bounds__(256)
void k2_softmax(float* out) {
  const int lane = threadIdx.x & 63;
  const int row = blockIdx.x * 4 + (threadIdx.x >> 6);
  float* Srow = out + (size_t)row * 2048 + 1024;
  float4 v[4];
#pragma unroll
  for (int s = 0; s < 4; ++s) v[s] = *(const float4*)(Srow + lane * 4 + s * 256);
  float m = -1e30f;
#pragma unroll
  for (int s = 0; s < 4; ++s)
    m = fmaxf(m, fmaxf(fmaxf(v[s].x, v[s].y), fmaxf(v[s].z, v[s].w)));
#pragma unroll
  for (int o = 32; o > 0; o >>= 1) m = fmaxf(m, __shfl_xor(m, o));
  float e[16];
  float sum = 0.f;
#pragma unroll
  for (int s = 0; s < 4; ++s) {
    e[4 * s + 0] = __expf(v[s].x - m);
    e[4 * s + 1] = __expf(v[s].y - m);
    e[4 * s + 2] = __expf(v[s].z - m);
    e[4 * s + 3] = __expf(v[s].w - m);
    sum += e[4 * s + 0] + e[4 * s + 1] + e[4 * s + 2] + e[4 * s + 3];
  }
#pragma unroll
  for (int o = 32; o > 0; o >>= 1) sum += __shfl_xor(sum, o);
  const float inv = 1.0f / sum;
  uint32_t* Prow = (uint32_t*)(out + (size_t)row * 2048);
#pragma unroll
  for (int s = 0; s < 4; ++s) {
    *(uint2*)&Prow[lane * 2 + s * 128] =
        make_uint2(pk2(e[4 * s + 0] * inv, e[4 * s + 1] * inv),
                   pk2(e[4 * s + 2] * inv, e[4 * s + 3] * inv));
  }
}

// ---------------------------------------------------------------------------
// K3: ctx[t][d] = sum_e P[t][e] * enc[e][d], fp16 MFMA.
// A = P fp16, frags loaded DIRECTLY from global (16B/lane, 64B segments).
// B = enc fp32 -> fp16, transposed at staging: each thread loads a 4x4 (e,d)
// block via 4 coalesced dwordx4 row-loads, packs along e, 4 ds_write_b64 into
// Bt[d][e] with pitch 36 halves (18 dw) -> conflict-minimal writes AND reads.
// Writes out[b,t,1024+d].
// ---------------------------------------------------------------------------
__global__ __launch_bounds__(256, 2)
void k3_av(const float* __restrict__ enc, float* __restrict__ out) {
  __shared__ uint32_t BS[128 * 18];  // [128 d][36 halves] (32 used + 4 pad)
  const int tid = threadIdx.x, lane = tid & 63, wave = tid >> 6;
  const int wm = wave >> 1, wn = wave & 1;
  const int b = blockIdx.z;
  const int t0 = blockIdx.y * 128, d0 = blockIdx.x * 128;
  const float* V = enc + (size_t)b * TE * DD;
  const _Float16* Pb = (const _Float16*)(out + (size_t)b * TD * 2048);

  const int lr = lane & 15, q = lane >> 4;
  size_t arow[4];
#pragma unroll
  for (int i = 0; i < 4; ++i)
    arow[i] = (size_t)(t0 + wm * 64 + i * 16 + lr) * 4096 + q * 8;
  int boffd[4];
#pragma unroll
  for (int i = 0; i < 4; ++i) boffd[i] = (wn * 64 + i * 16 + lr) * 18 + q * 4;

  // B staging mapping: eq = tid&7 (e-quad), u = (tid>>3)&31 (d-quad)
  const int eq = tid & 7, u = (tid >> 3) & 31;
  const float* vptr = V + (size_t)(eq * 4) * DD + d0 + u * 4;
  const int wbase = (u * 4) * 18 + eq * 2;

  f32x4 acc[4][4] = {};

  for (int e0k = 0; e0k < TE; e0k += 32) {
    const float4 v0 = *(const float4*)(vptr + 0 * (size_t)DD);
    const float4 v1 = *(const float4*)(vptr + 1 * (size_t)DD);
    const float4 v2 = *(const float4*)(vptr + 2 * (size_t)DD);
    const float4 v3 = *(const float4*)(vptr + 3 * (size_t)DD);
    // in-register 4x4 transpose: for each d, pack 4 consecutive e values
    *(uint2*)&BS[wbase + 0 * 18] = make_uint2(pk2(v0.x, v1.x), pk2(v2.x, v3.x));
    *(uint2*)&BS[wbase + 1 * 18] = make_uint2(pk2(v0.y, v1.y), pk2(v2.y, v3.y));
    *(uint2*)&BS[wbase + 2 * 18] = make_uint2(pk2(v0.z, v1.z), pk2(v2.z, v3.z));
    *(uint2*)&BS[wbase + 3 * 18] = make_uint2(pk2(v0.w, v1.w), pk2(v2.w, v3.w));
    __syncthreads();

    f16x8 af[4];
#pragma unroll
    for (int mi = 0; mi < 4; ++mi)
      af[mi] = *(const f16x8*)(Pb + arow[mi] + e0k);
#pragma unroll
    for (int ni = 0; ni < 4; ++ni) {
      const uint2 lo = *(const uint2*)&BS[boffd[ni]];
      const uint2 hi = *(const uint2*)&BS[boffd[ni] + 2];
      const uint4 bb = make_uint4(lo.x, lo.y, hi.x, hi.y);
      const f16x8 bf = __builtin_bit_cast(f16x8, bb);
#pragma unroll
      for (int mi = 0; mi < 4; ++mi)
        acc[mi][ni] =
            __builtin_amdgcn_mfma_f32_16x16x32_f16(af[mi], bf, acc[mi][ni], 0, 0, 0);
    }
    __syncthreads();
    vptr += 32 * (size_t)DD;
  }

  float* outb = out + (size_t)b * TD * 2048 + 1024;
  const int tb = t0 + wm * 64 + q * 4;
  const int db = d0 + wn * 64 + lr;
#pragma unroll
  for (int mi = 0; mi < 4; ++mi)
#pragma unroll
    for (int ni = 0; ni < 4; ++ni)
#pragma unroll
      for (int i = 0; i < 4; ++i)
        outb[(size_t)(tb + mi * 16 + i) * 2048 + (db + ni * 16)] = acc[mi][ni][i];
}

// ---------------------------------------------------------------------------
// K4: copy decoder_outputs into out[b,t,0:1024] (after K3 consumed P).
// ---------------------------------------------------------------------------
__global__ __launch_bounds__(256)
void k4_copydec(const float4* __restrict__ dec4, float4* __restrict__ out4) {
  size_t g = (size_t)blockIdx.x * 512 + threadIdx.x;
#pragma unroll
  for (int s = 0; s < 2; ++s, g += 256) {
    size_t row = g >> 8, col = g & 255;  // 256 float4 per 1024-float row
    out4[row * 512 + col] = dec4[g];
  }
}

extern "C" void kernel_launch(void* const* d_in, const int* in_sizes, int n_in,
                              void* d_out, int out_size, void* d_ws, size_t ws_size,
                              hipStream_t stream) {
  const float* enc = (const float*)d_in[0];
  const float* dec = (const float*)d_in[1];
  float* out = (float*)d_out;

  hipLaunchKernelGGL(k1_scores, dim3(8, 8, 16), dim3(256), 0, stream, dec, enc, out);
  hipLaunchKernelGGL(k2_softmax, dim3(4096), dim3(256), 0, stream, out);
  hipLaunchKernelGGL(k3_av, dim3(8, 8, 16), dim3(256), 0, stream, enc, out);
  hipLaunchKernelGGL(k4_copydec, dim3(8192), dim3(256), 0, stream,
                     (const float4*)dec, (float4*)out);
}